// Round 7
// baseline (131.841 us; speedup 1.0000x reference)
//
#include <hip/hip_runtime.h>
#include <hip/hip_bf16.h>

typedef __attribute__((ext_vector_type(8))) __bf16 bf16x8;
typedef __attribute__((ext_vector_type(4))) float f32x4;
typedef __attribute__((ext_vector_type(4))) int int4v;

#define NB 8
#define NN 2048
#define ND 256
#define L2E 1.44269504f
#define AS1 __attribute__((address_space(1)))
#define AS3 __attribute__((address_space(3)))

// ---------------------------------------------------------------------------
// K2: per block recompute wl/wr = W^T a halves (L2-hot W), then row dots.
//   elc[bn]   = (-0.8*el - 16) * log2e
//   er2[bn*2] = (er - 16) * log2e,  er2[bn*2+1] = 0.2*er * log2e
// k3 exponent = max(er2.x, er2.y + elc) -> exp2
// ---------------------------------------------------------------------------
__global__ __launch_bounds__(256) void k2_elr(
    const float* __restrict__ x, const float* __restrict__ W,
    const float* __restrict__ a, float* __restrict__ elc,
    float* __restrict__ er2) {
  __shared__ float wls[ND], wrs[ND];
  int t = threadIdx.x;
  {
    float swl = 0.f, swr = 0.f;
    for (int o = 0; o < ND; ++o) {
      float wv = W[(long)o * ND + t];
      swl = fmaf(a[o], wv, swl);
      swr = fmaf(a[ND + o], wv, swr);
    }
    wls[t] = swl;
    wrs[t] = swr;
  }
  __syncthreads();
  int r = t >> 2, q = t & 3;
  long row = (long)blockIdx.x * 64 + r;
  const f32x4* xr = (const f32x4*)(x + row * ND);
  float sl = 0.f, sr = 0.f;
#pragma unroll
  for (int ii = 0; ii < 16; ++ii) {
    int idx = q + (ii << 2);
    f32x4 xv = xr[idx];
    f32x4 lv = *(const f32x4*)(wls + idx * 4);
    f32x4 rv = *(const f32x4*)(wrs + idx * 4);
    sl += xv[0] * lv[0] + xv[1] * lv[1] + xv[2] * lv[2] + xv[3] * lv[3];
    sr += xv[0] * rv[0] + xv[1] * rv[1] + xv[2] * rv[2] + xv[3] * rv[3];
  }
  sl += __shfl_xor(sl, 1);
  sl += __shfl_xor(sl, 2);
  sr += __shfl_xor(sr, 1);
  sr += __shfl_xor(sr, 2);
  if (q == 0) {
    elc[row] = (-0.8f * sl - 16.0f) * L2E;
    float2 v;
    v.x = (sr - 16.0f) * L2E;
    v.y = 0.2f * sr * L2E;
    *(float2*)(er2 + row * 2) = v;
  }
}

// ---------------------------------------------------------------------------
// K1: h = x @ W^T via bf16 MFMA; write hT2[b][jc][d][32] bf16 (chunk-
// contiguous: one 32-j chunk x 256 d = 16 KB sequential block).
// ---------------------------------------------------------------------------
__global__ __launch_bounds__(256) void k1_h(
    const float* __restrict__ x, const float* __restrict__ W,
    __bf16* __restrict__ hT2) {
  __shared__ __bf16 hlds[256 * 34];
  int tid = threadIdx.x;
  int wid = tid >> 6, lane = tid & 63;
  int msub = wid & 1, nh = wid >> 1;
  int lrow = lane & 15, kg = lane >> 4;
  int m0 = blockIdx.x * 32;
  int row = m0 + msub * 16 + lrow;

  f32x4 acc[8];
#pragma unroll
  for (int f = 0; f < 8; ++f) acc[f] = (f32x4){0.f, 0.f, 0.f, 0.f};

#pragma unroll
  for (int k0 = 0; k0 < ND; k0 += 32) {
    int kk = k0 + kg * 8;
    const f32x4* xa = (const f32x4*)(x + (long)row * ND + kk);
    f32x4 a0 = xa[0], a1 = xa[1];
    bf16x8 afrag;
    afrag[0] = (__bf16)a0[0]; afrag[1] = (__bf16)a0[1];
    afrag[2] = (__bf16)a0[2]; afrag[3] = (__bf16)a0[3];
    afrag[4] = (__bf16)a1[0]; afrag[5] = (__bf16)a1[1];
    afrag[6] = (__bf16)a1[2]; afrag[7] = (__bf16)a1[3];
#pragma unroll
    for (int f = 0; f < 8; ++f) {
      int o = nh * 128 + f * 16 + lrow;
      const f32x4* wb = (const f32x4*)(W + (long)o * ND + kk);
      f32x4 b0 = wb[0], b1 = wb[1];
      bf16x8 bfrag;
      bfrag[0] = (__bf16)b0[0]; bfrag[1] = (__bf16)b0[1];
      bfrag[2] = (__bf16)b0[2]; bfrag[3] = (__bf16)b0[3];
      bfrag[4] = (__bf16)b1[0]; bfrag[5] = (__bf16)b1[1];
      bfrag[6] = (__bf16)b1[2]; bfrag[7] = (__bf16)b1[3];
      acc[f] = __builtin_amdgcn_mfma_f32_16x16x32_bf16(afrag, bfrag, acc[f], 0, 0, 0);
    }
  }

#pragma unroll
  for (int f = 0; f < 8; ++f) {
    int d = nh * 128 + f * 16 + lrow;
#pragma unroll
    for (int r = 0; r < 4; ++r) {
      int nloc = msub * 16 + kg * 4 + r;
      hlds[d * 34 + nloc] = (__bf16)acc[f][r];
    }
  }
  __syncthreads();
  {
    int b = m0 >> 11;
    int jc = (m0 & (NN - 1)) >> 5;
    const int* src = (const int*)(hlds + tid * 34);
    int tmp[16];
#pragma unroll
    for (int j = 0; j < 16; ++j) tmp[j] = src[j];
    __bf16* dst = hT2 + (((long)b * 64 + jc) * 256 + tid) * 32;
#pragma unroll
    for (int j = 0; j < 4; ++j)
      *(int4v*)(dst + j * 8) = *(int4v*)(tmp + j * 4);
  }
}

// ---------------------------------------------------------------------------
// K3: fused adj-stream + mask + softmax + PV. 512 thr (8 waves: isub=w&1,
// dh=w>>1 -> 64-d quarter). 32-j chunks, 4 LDS buffers, 3-chunk prefetch
// distance, exact counted vmcnt(8) (4 VMEM insts/chunk/thread: 2 hT-lds +
// 2 adj-reg). er2 staged once to LDS. hT stage fully coalesced (chunk-
// contiguous layout); ds_read slot swizzle -> 2-way (free) banks.
// ---------------------------------------------------------------------------
__global__ __launch_bounds__(512, 4) void k3_main(
    const int* __restrict__ adj, const __bf16* __restrict__ hT2,
    const float* __restrict__ elc, const float* __restrict__ er2,
    float* __restrict__ out) {
  __shared__ __bf16 hbuf[4][8192];  // 4 x 16 KB
  __shared__ float er_lds[NN * 2];  // 16 KB  (total 80 KB -> 2 blocks/CU)

  int blk = blockIdx.x;
  int b = blk & 7;    // batch -> XCD pin
  int it = blk >> 3;  // i-tile 0..63
  int tid = threadIdx.x;
  int wid = tid >> 6, lane = tid & 63;
  int isub = wid & 1, dh = wid >> 1;  // dh 0..3: 64-d quarter
  int lrow = lane & 15, kg = lane >> 4;
  int irow = it * 32 + isub * 16 + lrow;

  const __bf16* hT2b = hT2 + (long)b * 64 * 8192;
  const int* adjrow = adj + ((long)b * NN + irow) * NN;
  const float* er2b = er2 + (long)b * NN * 2;
  float c1s = elc[b * NN + irow];
  int kg8 = kg * 8;

  // one-time er2 stage (2 VMEM insts; drained by the first WAITB)
  __builtin_amdgcn_global_load_lds((const AS1 void*)(er2b + tid * 4),
                                   (AS3 void*)(er_lds + tid * 4), 16, 0, 0);
  __builtin_amdgcn_global_load_lds((const AS1 void*)(er2b + 2048 + tid * 4),
                                   (AS3 void*)(er_lds + 2048 + tid * 4), 16, 0, 0);

  // stage addressing: dest 16B-unit idx = inst*512+tid -> (d=idx>>2, slot=idx&3)
  // logical j-slot jlog = slot ^ (d&3) ^ ((d>>2)&3)  (inst-invariant for d+128)
  int d0 = tid >> 2, slot = tid & 3;
  int jlog = slot ^ (d0 & 3) ^ ((d0 >> 2) & 3);
  const __bf16* sgbase = hT2b + d0 * 32 + jlog * 8;

  // ds_read: byte = d_r*64 + slot_r*16, slot_r = kg^(lrow&3)^((lrow>>2)&3)
  int slot_r = kg ^ (lrow & 3) ^ ((lrow >> 2) & 3);
  int hoff = (dh * 64 + lrow) * 64 + slot_r * 16;  // +f*1024 per frag
  int d_base = dh * 64 + lrow;

  f32x4 acc[4];
#pragma unroll
  for (int f = 0; f < 4; ++f) acc[f] = (f32x4){0.f, 0.f, 0.f, 0.f};
  float den = 0.f;

  int4v aj0_0, aj1_0, aj0_1, aj1_1, aj0_2, aj1_2, aj0_3, aj1_3;

#define STAGEH(BI, TCV)                                                     \
  {                                                                         \
    const __bf16* s_ = sgbase + (long)(TCV)*8192;                           \
    __builtin_amdgcn_global_load_lds((const AS1 void*)(s_),                 \
                                     (AS3 void*)(&hbuf[BI][tid * 8]), 16, 0, 0); \
    __builtin_amdgcn_global_load_lds(                                       \
        (const AS1 void*)(s_ + 4096),                                       \
        (AS3 void*)(&hbuf[BI][4096 + tid * 8]), 16, 0, 0);                  \
  }

#define LOADADJ(S, TCV)                                                     \
  {                                                                         \
    const int* ap_ = adjrow + (TCV)*32 + kg8;                               \
    aj0_##S = *(const int4v*)(ap_);                                         \
    aj1_##S = *(const int4v*)(ap_ + 4);                                     \
  }

#define COMPUTE(BI, S, TCV)                                                 \
  {                                                                         \
    const float* ep_ = er_lds + ((TCV)*32 + kg8) * 2;                       \
    f32x4 e0 = *(const f32x4*)(ep_);                                        \
    f32x4 e1 = *(const f32x4*)(ep_ + 4);                                    \
    f32x4 e2 = *(const f32x4*)(ep_ + 8);                                    \
    f32x4 e3 = *(const f32x4*)(ep_ + 12);                                   \
    bf16x8 pfrag;                                                           \
    float ps = 0.f;                                                         \
    _Pragma("unroll") for (int e = 0; e < 8; ++e) {                         \
      f32x4 ev = (e < 2) ? e0 : (e < 4) ? e1 : (e < 6) ? e2 : e3;           \
      float x16 = ev[(e & 1) * 2];                                          \
      float x02 = ev[(e & 1) * 2 + 1];                                      \
      int aj = (e < 4) ? aj0_##S[e] : aj1_##S[e & 3];                       \
      float m = fmaxf(x16, x02 + c1s);                                      \
      float p = __builtin_amdgcn_exp2f(m);                                  \
      p = aj ? p : 0.0f;                                                    \
      ps += p;                                                              \
      pfrag[e] = (__bf16)p;                                                 \
    }                                                                       \
    den += ps;                                                              \
    const char* hb = (const char*)&hbuf[BI][0];                             \
    __builtin_amdgcn_s_setprio(1);                                          \
    _Pragma("unroll") for (int f = 0; f < 4; ++f) {                         \
      bf16x8 bfr = *(const bf16x8*)(hb + hoff + f * 1024);                  \
      acc[f] = __builtin_amdgcn_mfma_f32_16x16x32_bf16(pfrag, bfr, acc[f], 0, 0, 0); \
    }                                                                       \
    __builtin_amdgcn_s_setprio(0);                                          \
  }

#define WAITB(VMN)                                       \
  asm volatile("s_waitcnt vmcnt(" VMN ")" ::: "memory"); \
  __builtin_amdgcn_s_barrier();

  // prologue: chunks 0,1,2 in flight (+ er2 oldest)
  LOADADJ(0, 0); STAGEH(0, 0);
  LOADADJ(1, 1); STAGEH(1, 1);
  LOADADJ(2, 2); STAGEH(2, 2);

  for (int t4 = 0; t4 < 15; ++t4) {
    int tc = t4 * 4;  // computes tc..tc+3, stages tc+3..tc+6 (max 62)
    WAITB("8"); STAGEH(3, tc + 3); LOADADJ(3, tc + 3); COMPUTE(0, 0, tc);
    WAITB("8"); STAGEH(0, tc + 4); LOADADJ(0, tc + 4); COMPUTE(1, 1, tc + 1);
    WAITB("8"); STAGEH(1, tc + 5); LOADADJ(1, tc + 5); COMPUTE(2, 2, tc + 2);
    WAITB("8"); STAGEH(2, tc + 6); LOADADJ(2, tc + 6); COMPUTE(3, 3, tc + 3);
  }
  // epilogue: chunks 60..63
  WAITB("8"); STAGEH(3, 63); LOADADJ(3, 63); COMPUTE(0, 0, 60);
  WAITB("8"); COMPUTE(1, 1, 61);
  WAITB("4"); COMPUTE(2, 2, 62);
  WAITB("0"); COMPUTE(3, 3, 63);

#undef STAGEH
#undef LOADADJ
#undef COMPUTE
#undef WAITB

  // den: sum across the 4 k-groups (lanes with same l&15)
  den += __shfl_xor(den, 16);
  den += __shfl_xor(den, 32);
  float rdiv[4];
#pragma unroll
  for (int r = 0; r < 4; ++r) rdiv[r] = 1.0f / __shfl(den, kg * 4 + r);

  float* outb = out + ((long)b * NN + it * 32 + isub * 16) * ND;
#pragma unroll
  for (int f = 0; f < 4; ++f) {
    int dcol = d_base + f * 16;
#pragma unroll
    for (int r = 0; r < 4; ++r)
      outb[(long)(kg * 4 + r) * ND + dcol] = acc[f][r] * rdiv[r];
  }
}

// ---------------------------------------------------------------------------
extern "C" void kernel_launch(void* const* d_in, const int* in_sizes, int n_in,
                              void* d_out, int out_size, void* d_ws,
                              size_t ws_size, hipStream_t stream) {
  const float* x = (const float*)d_in[0];
  const int* adj = (const int*)d_in[1];
  const float* W = (const float*)d_in[2];
  const float* a = (const float*)d_in[3];
  float* out = (float*)d_out;

  char* ws = (char*)d_ws;
  const size_t base = 8u * 1024u * 1024u;
  __bf16* hT2 = (__bf16*)ws;                  // 8 MB
  float* elc = (float*)(ws + base);           // 64 KB
  float* er2 = (float*)(ws + base + 65536u);  // 128 KB

  k1_h<<<dim3(512), dim3(256), 0, stream>>>(x, W, hT2);
  k2_elr<<<dim3(256), dim3(256), 0, stream>>>(x, W, a, elc, er2);
  k3_main<<<dim3(512), dim3(512), 0, stream>>>(adj, hT2, elc, er2, out);
}

// Round 8
// 131.727 us; speedup vs baseline: 1.0009x; 1.0009x over previous
//
#include <hip/hip_runtime.h>
#include <hip/hip_bf16.h>

typedef __attribute__((ext_vector_type(8))) __bf16 bf16x8;
typedef __attribute__((ext_vector_type(4))) float f32x4;
typedef __attribute__((ext_vector_type(4))) int int4v;

#define NB 8
#define NN 2048
#define ND 256
#define L2E 1.44269504f
#define AS1 __attribute__((address_space(1)))
#define AS3 __attribute__((address_space(3)))

// ---------------------------------------------------------------------------
// K5: pack adj (134 MB int32) into bitmask (4.2 MB). Pure linear HBM stream:
// each wave reads 256 B contiguous, one uint64 out via ballot.
// ---------------------------------------------------------------------------
__global__ __launch_bounds__(256) void k5_pack(
    const int* __restrict__ adj, unsigned long long* __restrict__ mask) {
  const long NSEG = (long)NB * NN * (NN / 64);  // 524288
  int lane = threadIdx.x & 63;
  long gw = (((long)blockIdx.x * 256 + threadIdx.x) >> 6);
  long stride = ((long)gridDim.x * 256) >> 6;
  for (long s = gw; s < NSEG; s += stride) {
    int v = adj[s * 64 + lane];
    unsigned long long m = __ballot(v != 0);
    if (lane == 0) mask[s] = m;
  }
}

// ---------------------------------------------------------------------------
// K2: per block recompute wl/wr = W^T a halves (L2-hot W), then row dots.
//   elc[bn]   = (-0.8*el - 16) * log2e
//   er2[bn*2] = (er - 16) * log2e,  er2[bn*2+1] = 0.2*er * log2e
// k3 exponent = max(er2.x, er2.y + elc) -> exp2
// ---------------------------------------------------------------------------
__global__ __launch_bounds__(256) void k2_elr(
    const float* __restrict__ x, const float* __restrict__ W,
    const float* __restrict__ a, float* __restrict__ elc,
    float* __restrict__ er2) {
  __shared__ float wls[ND], wrs[ND];
  int t = threadIdx.x;
  {
    float swl = 0.f, swr = 0.f;
    for (int o = 0; o < ND; ++o) {
      float wv = W[(long)o * ND + t];
      swl = fmaf(a[o], wv, swl);
      swr = fmaf(a[ND + o], wv, swr);
    }
    wls[t] = swl;
    wrs[t] = swr;
  }
  __syncthreads();
  int r = t >> 2, q = t & 3;
  long row = (long)blockIdx.x * 64 + r;
  const f32x4* xr = (const f32x4*)(x + row * ND);
  float sl = 0.f, sr = 0.f;
#pragma unroll
  for (int ii = 0; ii < 16; ++ii) {
    int idx = q + (ii << 2);
    f32x4 xv = xr[idx];
    f32x4 lv = *(const f32x4*)(wls + idx * 4);
    f32x4 rv = *(const f32x4*)(wrs + idx * 4);
    sl += xv[0] * lv[0] + xv[1] * lv[1] + xv[2] * lv[2] + xv[3] * lv[3];
    sr += xv[0] * rv[0] + xv[1] * rv[1] + xv[2] * rv[2] + xv[3] * rv[3];
  }
  sl += __shfl_xor(sl, 1);
  sl += __shfl_xor(sl, 2);
  sr += __shfl_xor(sr, 1);
  sr += __shfl_xor(sr, 2);
  if (q == 0) {
    elc[row] = (-0.8f * sl - 16.0f) * L2E;
    float2 v;
    v.x = (sr - 16.0f) * L2E;
    v.y = 0.2f * sr * L2E;
    *(float2*)(er2 + row * 2) = v;
  }
}

// ---------------------------------------------------------------------------
// K1: h = x @ W^T via bf16 MFMA; write hT2[b][jc][d][32] bf16 (chunk-
// contiguous: one 32-j chunk x 256 d = 16 KB sequential block).
// ---------------------------------------------------------------------------
__global__ __launch_bounds__(256) void k1_h(
    const float* __restrict__ x, const float* __restrict__ W,
    __bf16* __restrict__ hT2) {
  __shared__ __bf16 hlds[256 * 34];
  int tid = threadIdx.x;
  int wid = tid >> 6, lane = tid & 63;
  int msub = wid & 1, nh = wid >> 1;
  int lrow = lane & 15, kg = lane >> 4;
  int m0 = blockIdx.x * 32;
  int row = m0 + msub * 16 + lrow;

  f32x4 acc[8];
#pragma unroll
  for (int f = 0; f < 8; ++f) acc[f] = (f32x4){0.f, 0.f, 0.f, 0.f};

#pragma unroll
  for (int k0 = 0; k0 < ND; k0 += 32) {
    int kk = k0 + kg * 8;
    const f32x4* xa = (const f32x4*)(x + (long)row * ND + kk);
    f32x4 a0 = xa[0], a1 = xa[1];
    bf16x8 afrag;
    afrag[0] = (__bf16)a0[0]; afrag[1] = (__bf16)a0[1];
    afrag[2] = (__bf16)a0[2]; afrag[3] = (__bf16)a0[3];
    afrag[4] = (__bf16)a1[0]; afrag[5] = (__bf16)a1[1];
    afrag[6] = (__bf16)a1[2]; afrag[7] = (__bf16)a1[3];
#pragma unroll
    for (int f = 0; f < 8; ++f) {
      int o = nh * 128 + f * 16 + lrow;
      const f32x4* wb = (const f32x4*)(W + (long)o * ND + kk);
      f32x4 b0 = wb[0], b1 = wb[1];
      bf16x8 bfrag;
      bfrag[0] = (__bf16)b0[0]; bfrag[1] = (__bf16)b0[1];
      bfrag[2] = (__bf16)b0[2]; bfrag[3] = (__bf16)b0[3];
      bfrag[4] = (__bf16)b1[0]; bfrag[5] = (__bf16)b1[1];
      bfrag[6] = (__bf16)b1[2]; bfrag[7] = (__bf16)b1[3];
      acc[f] = __builtin_amdgcn_mfma_f32_16x16x32_bf16(afrag, bfrag, acc[f], 0, 0, 0);
    }
  }

#pragma unroll
  for (int f = 0; f < 8; ++f) {
    int d = nh * 128 + f * 16 + lrow;
#pragma unroll
    for (int r = 0; r < 4; ++r) {
      int nloc = msub * 16 + kg * 4 + r;
      hlds[d * 34 + nloc] = (__bf16)acc[f][r];
    }
  }
  __syncthreads();
  {
    int b = m0 >> 11;
    int jc = (m0 & (NN - 1)) >> 5;
    const int* src = (const int*)(hlds + tid * 34);
    int tmp[16];
#pragma unroll
    for (int j = 0; j < 16; ++j) tmp[j] = src[j];
    __bf16* dst = hT2 + (((long)b * 64 + jc) * 256 + tid) * 32;
#pragma unroll
    for (int j = 0; j < 4; ++j)
      *(int4v*)(dst + j * 8) = *(int4v*)(tmp + j * 4);
  }
}

// ---------------------------------------------------------------------------
// K3: fused mask + softmax + PV. 512 thr (8 waves: isub=w&1, dh=w>>1 64-d
// quarter). 32-j chunks; hT triple-buffered via global_load_lds (2 insts/
// thread/chunk, r6-proven zero-conflict swizzle pair). Block's full mask tile
// (8 KB, stride-65-padded) + er2 (16 KB) staged once. Main loop has ZERO
// global loads; exact counted vmcnt(2) (2-chunk slack vs L2-hit hT loads).
// p_ij = bit ? exp2(max(er2.x, er2.y + elc_i)) : 0.
// LDS = 48 + 16 + 8.125 = 72.1 KB -> 2 blocks/CU.
// ---------------------------------------------------------------------------
__global__ __launch_bounds__(512, 4) void k3_main(
    const unsigned* __restrict__ mask32, const __bf16* __restrict__ hT2,
    const float* __restrict__ elc, const float* __restrict__ er2,
    float* __restrict__ out) {
  __shared__ __bf16 hbuf[3][8192];      // 3 x 16 KB
  __shared__ float er_lds[NN * 2];      // 16 KB
  __shared__ unsigned mask_lds[32 * 65];  // 8.125 KB

  int blk = blockIdx.x;
  int b = blk & 7;    // batch -> XCD pin
  int it = blk >> 3;  // i-tile 0..63
  int tid = threadIdx.x;
  int wid = tid >> 6, lane = tid & 63;
  int isub = wid & 1, dh = wid >> 1;  // dh 0..3: 64-d quarter
  int lrow = lane & 15, kg = lane >> 4;
  int irow = it * 32 + isub * 16 + lrow;

  const __bf16* hT2b = hT2 + (long)b * 64 * 8192;
  const unsigned* maskb = mask32 + ((long)b * NN + (long)it * 32) * 64;
  const float* er2b = er2 + (long)b * NN * 2;
  float c1s = elc[b * NN + irow];
  int kg8 = kg * 8;

  // ---- prologue staging ----
  // 1) mask tile: 2048 words contiguous; reg-load now, padded ds_write later.
  int4v mw = *(const int4v*)(maskb + tid * 4);
  // 2) er2 -> LDS (2 gload_lds insts)
  __builtin_amdgcn_global_load_lds((const AS1 void*)(er2b + tid * 4),
                                   (AS3 void*)(er_lds + tid * 4), 16, 0, 0);
  __builtin_amdgcn_global_load_lds((const AS1 void*)(er2b + 2048 + tid * 4),
                                   (AS3 void*)(er_lds + 2048 + tid * 4), 16, 0, 0);

  // stage addressing (r6 pair): dest 16B-unit idx = inst*512+tid ->
  // (d=idx>>2, slot=idx&3), logical j-slice = slot ^ ((d>>1)&3) (inst-inv).
  int d0 = tid >> 2, slot = tid & 3;
  int jlog = slot ^ ((d0 >> 1) & 3);
  const __bf16* sgbase = hT2b + d0 * 32 + jlog * 8;

#define STAGEH(BI, TCV)                                                      \
  {                                                                          \
    const __bf16* s_ = sgbase + (long)(TCV)*8192;                            \
    __builtin_amdgcn_global_load_lds((const AS1 void*)(s_),                  \
                                     (AS3 void*)(&hbuf[BI][tid * 8]), 16, 0, 0); \
    __builtin_amdgcn_global_load_lds(                                        \
        (const AS1 void*)(s_ + 4096),                                        \
        (AS3 void*)(&hbuf[BI][4096 + tid * 8]), 16, 0, 0);                   \
  }

  // 3) hT chunks 0,1 in flight
  STAGEH(0, 0);
  STAGEH(1, 1);

  // 4) mask regs -> padded LDS (wait only the mask load: 6 younger VMEM)
  asm volatile("s_waitcnt vmcnt(6)" ::: "memory");
  {
    int mrow = tid >> 4, mcol = (tid & 15) * 4;
    *(int4v*)(mask_lds + mrow * 65 + mcol) = mw;
  }
  asm volatile("s_waitcnt lgkmcnt(0)" ::: "memory");
  __builtin_amdgcn_s_barrier();

  // ds_read swizzle (r6 pair): byte = d*64 + (kg^((lrow>>1)&3))*16, d-terms
  // dh*64, f*16 do not affect (d>>1)&3.
  int hoff = (dh * 64 + lrow) * 64 + (kg ^ ((lrow >> 1) & 3)) * 16;
  int d_base = dh * 64 + lrow;
  int mbase = (isub * 16 + lrow) * 65;

  f32x4 acc[4];
#pragma unroll
  for (int f = 0; f < 4; ++f) acc[f] = (f32x4){0.f, 0.f, 0.f, 0.f};
  float den = 0.f;

#define COMPUTE(BI, TCV)                                                     \
  {                                                                          \
    unsigned msh = mask_lds[mbase + (TCV)] >> kg8;                           \
    const float* ep_ = er_lds + ((TCV)*32 + kg8) * 2;                        \
    f32x4 e0 = *(const f32x4*)(ep_);                                         \
    f32x4 e1 = *(const f32x4*)(ep_ + 4);                                     \
    f32x4 e2 = *(const f32x4*)(ep_ + 8);                                     \
    f32x4 e3 = *(const f32x4*)(ep_ + 12);                                    \
    bf16x8 pfrag;                                                            \
    float ps = 0.f;                                                          \
    _Pragma("unroll") for (int e = 0; e < 8; ++e) {                          \
      f32x4 ev = (e < 2) ? e0 : (e < 4) ? e1 : (e < 6) ? e2 : e3;            \
      float x16 = ev[(e & 1) * 2];                                           \
      float x02 = ev[(e & 1) * 2 + 1];                                       \
      float m = fmaxf(x16, x02 + c1s);                                       \
      float p = __builtin_amdgcn_exp2f(m);                                   \
      p = ((msh >> e) & 1u) ? p : 0.0f;                                      \
      ps += p;                                                               \
      pfrag[e] = (__bf16)p;                                                  \
    }                                                                        \
    den += ps;                                                               \
    const char* hb = (const char*)&hbuf[BI][0];                              \
    __builtin_amdgcn_s_setprio(1);                                           \
    _Pragma("unroll") for (int f = 0; f < 4; ++f) {                          \
      bf16x8 bfr = *(const bf16x8*)(hb + hoff + f * 1024);                   \
      acc[f] = __builtin_amdgcn_mfma_f32_16x16x32_bf16(pfrag, bfr, acc[f], 0, 0, 0); \
    }                                                                        \
    __builtin_amdgcn_s_setprio(0);                                           \
  }

#define WAITB(VMN)                                       \
  asm volatile("s_waitcnt vmcnt(" VMN ")" ::: "memory"); \
  __builtin_amdgcn_s_barrier();

  // main: chunks 0..59 (stages 2..61); buffers cycle tc%3
  for (int t3 = 0; t3 < 20; ++t3) {
    int tc = t3 * 3;
    WAITB("2"); STAGEH(2, tc + 2); COMPUTE(0, tc);
    WAITB("2"); STAGEH(0, tc + 3); COMPUTE(1, tc + 1);
    WAITB("2"); STAGEH(1, tc + 4); COMPUTE(2, tc + 2);
  }
  // epilogue: 60..63 (stage 62,63)
  WAITB("2"); STAGEH(2, 62); COMPUTE(0, 60);
  WAITB("2"); STAGEH(0, 63); COMPUTE(1, 61);
  WAITB("2"); COMPUTE(2, 62);
  WAITB("0"); COMPUTE(0, 63);

#undef STAGEH
#undef COMPUTE
#undef WAITB

  // den: sum across the 4 k-groups (lanes with same l&15)
  den += __shfl_xor(den, 16);
  den += __shfl_xor(den, 32);
  float rdiv[4];
#pragma unroll
  for (int r = 0; r < 4; ++r) rdiv[r] = 1.0f / __shfl(den, kg * 4 + r);

  float* outb = out + ((long)b * NN + it * 32 + isub * 16) * ND;
#pragma unroll
  for (int f = 0; f < 4; ++f) {
    int dcol = d_base + f * 16;
#pragma unroll
    for (int r = 0; r < 4; ++r)
      outb[(long)(kg * 4 + r) * ND + dcol] = acc[f][r] * rdiv[r];
  }
}

// ---------------------------------------------------------------------------
extern "C" void kernel_launch(void* const* d_in, const int* in_sizes, int n_in,
                              void* d_out, int out_size, void* d_ws,
                              size_t ws_size, hipStream_t stream) {
  const float* x = (const float*)d_in[0];
  const int* adj = (const int*)d_in[1];
  const float* W = (const float*)d_in[2];
  const float* a = (const float*)d_in[3];
  float* out = (float*)d_out;

  char* ws = (char*)d_ws;
  const size_t base = 8u * 1024u * 1024u;
  __bf16* hT2 = (__bf16*)ws;                  // 8 MB
  float* elc = (float*)(ws + base);           // 64 KB
  float* er2 = (float*)(ws + base + 65536u);  // 128 KB
  unsigned long long* mask =
      (unsigned long long*)(ws + base + 262144u);  // 4 MB

  k5_pack<<<dim3(2048), dim3(256), 0, stream>>>(adj, mask);
  k1_h<<<dim3(512), dim3(256), 0, stream>>>(x, W, hT2);
  k2_elr<<<dim3(256), dim3(256), 0, stream>>>(x, W, a, elc, er2);
  k3_main<<<dim3(512), dim3(512), 0, stream>>>((const unsigned*)mask, hT2, elc,
                                               er2, out);
}

// Round 9
// 125.500 us; speedup vs baseline: 1.0505x; 1.0496x over previous
//
#include <hip/hip_runtime.h>
#include <hip/hip_bf16.h>

typedef __attribute__((ext_vector_type(8))) __bf16 bf16x8;
typedef __attribute__((ext_vector_type(4))) float f32x4;
typedef __attribute__((ext_vector_type(4))) int int4v;

#define NB 8
#define NN 2048
#define ND 256
#define L2E 1.44269504f
#define AS1 __attribute__((address_space(1)))
#define AS3 __attribute__((address_space(3)))

// ---------------------------------------------------------------------------
// K2: per block recompute wl/wr = W^T a halves (L2-hot W), then row dots.
//   elc[bn] = (-0.8*el - 16) * log2e
//   erx[bn] = (er - 16) * log2e          (x02 = 0.2*x16 + 3.2*log2e in k3)
// ---------------------------------------------------------------------------
__global__ __launch_bounds__(256) void k2_elr(
    const float* __restrict__ x, const float* __restrict__ W,
    const float* __restrict__ a, float* __restrict__ elc,
    float* __restrict__ erx) {
  __shared__ float wls[ND], wrs[ND];
  int t = threadIdx.x;
  {
    float swl = 0.f, swr = 0.f;
    for (int o = 0; o < ND; ++o) {
      float wv = W[(long)o * ND + t];
      swl = fmaf(a[o], wv, swl);
      swr = fmaf(a[ND + o], wv, swr);
    }
    wls[t] = swl;
    wrs[t] = swr;
  }
  __syncthreads();
  int r = t >> 2, q = t & 3;
  long row = (long)blockIdx.x * 64 + r;
  const f32x4* xr = (const f32x4*)(x + row * ND);
  float sl = 0.f, sr = 0.f;
#pragma unroll
  for (int ii = 0; ii < 16; ++ii) {
    int idx = q + (ii << 2);
    f32x4 xv = xr[idx];
    f32x4 lv = *(const f32x4*)(wls + idx * 4);
    f32x4 rv = *(const f32x4*)(wrs + idx * 4);
    sl += xv[0] * lv[0] + xv[1] * lv[1] + xv[2] * lv[2] + xv[3] * lv[3];
    sr += xv[0] * rv[0] + xv[1] * rv[1] + xv[2] * rv[2] + xv[3] * rv[3];
  }
  sl += __shfl_xor(sl, 1);
  sl += __shfl_xor(sl, 2);
  sr += __shfl_xor(sr, 1);
  sr += __shfl_xor(sr, 2);
  if (q == 0) {
    elc[row] = (-0.8f * sl - 16.0f) * L2E;
    erx[row] = (sr - 16.0f) * L2E;
  }
}

// ---------------------------------------------------------------------------
// K1: h = x @ W^T via bf16 MFMA; write hT2[b][jc][d][32] bf16 (chunk-
// contiguous: one 32-j chunk x 256 d = 16 KB sequential block).
// ---------------------------------------------------------------------------
__global__ __launch_bounds__(256) void k1_h(
    const float* __restrict__ x, const float* __restrict__ W,
    __bf16* __restrict__ hT2) {
  __shared__ __bf16 hlds[256 * 34];
  int tid = threadIdx.x;
  int wid = tid >> 6, lane = tid & 63;
  int msub = wid & 1, nh = wid >> 1;
  int lrow = lane & 15, kg = lane >> 4;
  int m0 = blockIdx.x * 32;
  int row = m0 + msub * 16 + lrow;

  f32x4 acc[8];
#pragma unroll
  for (int f = 0; f < 8; ++f) acc[f] = (f32x4){0.f, 0.f, 0.f, 0.f};

#pragma unroll
  for (int k0 = 0; k0 < ND; k0 += 32) {
    int kk = k0 + kg * 8;
    const f32x4* xa = (const f32x4*)(x + (long)row * ND + kk);
    f32x4 a0 = xa[0], a1 = xa[1];
    bf16x8 afrag;
    afrag[0] = (__bf16)a0[0]; afrag[1] = (__bf16)a0[1];
    afrag[2] = (__bf16)a0[2]; afrag[3] = (__bf16)a0[3];
    afrag[4] = (__bf16)a1[0]; afrag[5] = (__bf16)a1[1];
    afrag[6] = (__bf16)a1[2]; afrag[7] = (__bf16)a1[3];
#pragma unroll
    for (int f = 0; f < 8; ++f) {
      int o = nh * 128 + f * 16 + lrow;
      const f32x4* wb = (const f32x4*)(W + (long)o * ND + kk);
      f32x4 b0 = wb[0], b1 = wb[1];
      bf16x8 bfrag;
      bfrag[0] = (__bf16)b0[0]; bfrag[1] = (__bf16)b0[1];
      bfrag[2] = (__bf16)b0[2]; bfrag[3] = (__bf16)b0[3];
      bfrag[4] = (__bf16)b1[0]; bfrag[5] = (__bf16)b1[1];
      bfrag[6] = (__bf16)b1[2]; bfrag[7] = (__bf16)b1[3];
      acc[f] = __builtin_amdgcn_mfma_f32_16x16x32_bf16(afrag, bfrag, acc[f], 0, 0, 0);
    }
  }

#pragma unroll
  for (int f = 0; f < 8; ++f) {
    int d = nh * 128 + f * 16 + lrow;
#pragma unroll
    for (int r = 0; r < 4; ++r) {
      int nloc = msub * 16 + kg * 4 + r;
      hlds[d * 34 + nloc] = (__bf16)acc[f][r];
    }
  }
  __syncthreads();
  {
    int b = m0 >> 11;
    int jc = (m0 & (NN - 1)) >> 5;
    const int* src = (const int*)(hlds + tid * 34);
    int tmp[16];
#pragma unroll
    for (int j = 0; j < 16; ++j) tmp[j] = src[j];
    __bf16* dst = hT2 + (((long)b * 64 + jc) * 256 + tid) * 32;
#pragma unroll
    for (int j = 0; j < 4; ++j)
      *(int4v*)(dst + j * 8) = *(int4v*)(tmp + j * 4);
  }
}

// ---------------------------------------------------------------------------
// K3: fully fused adj-pack + mask + softmax + PV.
// 256 thr = 4 waves; wave = 2 rowgroups x 4 d-frags (64 d) -> zero B-read dup.
// Per 32-j phase: stage hT chunk t+2 (4 gload_lds), ballot-pack adj pair
// loaded 2 phases ago into XOR-banked mask_lds, load adj pair t/2+2 (4
// coalesced 256B reads), compute (16 exp2 + 8 MFMA). Exact vmcnt(8)/phase.
// LDS = 4x16K ring + 8K er + 8K mask = 80 KB -> 2 blocks/CU.
// ---------------------------------------------------------------------------
__global__ __launch_bounds__(256, 2) void k3_main(
    const int* __restrict__ adj, const __bf16* __restrict__ hT2,
    const float* __restrict__ elc, const float* __restrict__ erx,
    float* __restrict__ out) {
  __shared__ __bf16 hbuf[4][8192];     // 64 KB
  __shared__ float er_lds[NN];         // 8 KB
  __shared__ unsigned mask_lds[2048];  // 8 KB flat [row*64 + (w ^ (row&31))]

  int blk = blockIdx.x;
  int b = blk & 7;    // batch -> XCD pin
  int it = blk >> 3;  // i-tile 0..63
  int tid = threadIdx.x;
  int wid = tid >> 6, lane = tid & 63;
  int lrow = lane & 15, kg = lane >> 4;
  int kg8 = kg * 8;

  const __bf16* hT2b = hT2 + (long)b * 64 * 8192;
  const int* adjb = adj + ((long)b * NN + (long)it * 32) * NN;
  const int* adjw = adjb + (long)wid * 8 * NN;  // this wave's 8 adj rows
  const float* erxb = erx + (long)b * NN;

  // elc for this lane's two rows (VGPR loads, compiler-tracked)
  float c1s0 = elc[b * NN + it * 32 + lrow];
  float c1s1 = elc[b * NN + it * 32 + 16 + lrow];

  // er -> LDS (2 gload_lds)
  __builtin_amdgcn_global_load_lds((const AS1 void*)(erxb + tid * 4),
                                   (AS3 void*)(er_lds + tid * 4), 16, 0, 0);
  __builtin_amdgcn_global_load_lds((const AS1 void*)(erxb + 1024 + tid * 4),
                                   (AS3 void*)(er_lds + 1024 + tid * 4), 16, 0, 0);

  // hT stage addressing (r6-proven pair): dest unit idx = rr*256+tid;
  // d0 = tid>>2, slot = tid&3, jlog = slot ^ ((tid>>3)&3)  (rr-invariant).
  int d0 = tid >> 2, slot = tid & 3;
  int jlog = slot ^ ((tid >> 3) & 3);
  const __bf16* sgbase = hT2b + d0 * 32 + jlog * 8;

  // ds_read: d = wid*64 + f*16 + lrow; slot_r = kg ^ ((lrow>>1)&3)
  int hoff = (wid * 64 + lrow) * 64 + (kg ^ ((lrow >> 1) & 3)) * 16;

  f32x4 acc[2][4];
#pragma unroll
  for (int g = 0; g < 2; ++g)
#pragma unroll
    for (int f = 0; f < 4; ++f) acc[g][f] = (f32x4){0.f, 0.f, 0.f, 0.f};
  float den0 = 0.f, den1 = 0.f;

  int av0[4], av1[4];  // 2 adj register sets (pair-half each)

#define STAGEH(BI, TCV)                                                       \
  {                                                                           \
    const __bf16* s_ = sgbase + (long)(TCV)*8192;                             \
    _Pragma("unroll") for (int rr = 0; rr < 4; ++rr) {                        \
      __builtin_amdgcn_global_load_lds(                                       \
          (const AS1 void*)(s_ + rr * 2048),                                  \
          (AS3 void*)(&hbuf[BI][(rr * 256 + tid) * 8]), 16, 0, 0);            \
    }                                                                         \
  }

#define ADJLOAD(S, P, H)                                                      \
  {                                                                           \
    const int* ap_ = adjw + (long)(H)*4 * NN + (long)(P)*64 + lane;           \
    _Pragma("unroll") for (int i = 0; i < 4; ++i)                             \
        av##S[i] = ap_[(long)i * NN];                                         \
  }

#define BALLOT(S, P, H)                                                       \
  {                                                                           \
    _Pragma("unroll") for (int i = 0; i < 4; ++i) {                           \
      unsigned long long mb_ = __ballot(av##S[i] != 0);                       \
      int R_ = wid * 8 + (H)*4 + i;                                           \
      if (lane == 0) {                                                        \
        mask_lds[R_ * 64 + ((2 * (P)) ^ (R_ & 31))] = (unsigned)mb_;          \
        mask_lds[R_ * 64 + ((2 * (P) + 1) ^ (R_ & 31))] = (unsigned)(mb_ >> 32); \
      }                                                                       \
    }                                                                         \
  }

#define COMPUTE(BI, TCV)                                                      \
  {                                                                           \
    unsigned msh0 = mask_lds[lrow * 64 + ((TCV) ^ lrow)] >> kg8;              \
    unsigned msh1 = mask_lds[(lrow + 16) * 64 + ((TCV) ^ lrow ^ 16)] >> kg8;  \
    const float* ep_ = er_lds + (TCV)*32 + kg8;                               \
    f32x4 x16a = *(const f32x4*)(ep_);                                        \
    f32x4 x16b = *(const f32x4*)(ep_ + 4);                                    \
    bf16x8 pf0, pf1;                                                          \
    float ps0 = 0.f, ps1 = 0.f;                                               \
    _Pragma("unroll") for (int e = 0; e < 8; ++e) {                           \
      float x16 = (e < 4) ? x16a[e] : x16b[e - 4];                            \
      float x02 = fmaf(0.2f, x16, 4.61662413f);                               \
      float m0_ = fmaxf(x16, x02 + c1s0);                                     \
      float m1_ = fmaxf(x16, x02 + c1s1);                                     \
      float p0 = __builtin_amdgcn_exp2f(m0_);                                 \
      float p1 = __builtin_amdgcn_exp2f(m1_);                                 \
      p0 = ((msh0 >> e) & 1u) ? p0 : 0.0f;                                    \
      p1 = ((msh1 >> e) & 1u) ? p1 : 0.0f;                                    \
      ps0 += p0; ps1 += p1;                                                   \
      pf0[e] = (__bf16)p0; pf1[e] = (__bf16)p1;                               \
    }                                                                         \
    den0 += ps0; den1 += ps1;                                                 \
    const char* hb_ = (const char*)&hbuf[BI][0];                              \
    __builtin_amdgcn_s_setprio(1);                                            \
    _Pragma("unroll") for (int f = 0; f < 4; ++f) {                           \
      bf16x8 bfr = *(const bf16x8*)(hb_ + hoff + f * 1024);                   \
      acc[0][f] = __builtin_amdgcn_mfma_f32_16x16x32_bf16(pf0, bfr, acc[0][f], 0, 0, 0); \
      acc[1][f] = __builtin_amdgcn_mfma_f32_16x16x32_bf16(pf1, bfr, acc[1][f], 0, 0, 0); \
    }                                                                         \
    __builtin_amdgcn_s_setprio(0);                                            \
  }

#define WAITX(VMN)                                                        \
  asm volatile("s_waitcnt vmcnt(" VMN ") lgkmcnt(0)" ::: "memory");       \
  __builtin_amdgcn_s_barrier();

  // ---- prologue ----
  STAGEH(0, 0);
  STAGEH(1, 1);
  ADJLOAD(0, 0, 0);  // pair0 half0 -> set0
  ADJLOAD(1, 0, 1);  // pair0 half1 -> set1
  asm volatile("s_waitcnt vmcnt(0)" ::: "memory");  // one-time full drain
  BALLOT(0, 0, 0);
  BALLOT(1, 0, 1);
  ADJLOAD(0, 1, 0);  // pair1 half0 -> set0 (ballot at t=0)
  ADJLOAD(1, 1, 1);  // pair1 half1 -> set1 (ballot at t=1)
  asm volatile("s_waitcnt lgkmcnt(0)" ::: "memory");
  __builtin_amdgcn_s_barrier();

  // ---- main loop: phases t = 4T + t4, t = 0..59 ----
  for (int T = 0; T < 15; ++T) {
    int tc = T * 4;
    WAITX("8"); STAGEH(2, tc + 2); BALLOT(0, (tc >> 1) + 1, 0);
    ADJLOAD(0, (tc >> 1) + 2, 0); COMPUTE(0, tc);
    WAITX("8"); STAGEH(3, tc + 3); BALLOT(1, (tc >> 1) + 1, 1);
    ADJLOAD(1, (tc >> 1) + 2, 1); COMPUTE(1, tc + 1);
    WAITX("8"); STAGEH(0, tc + 4); BALLOT(0, (tc >> 1) + 2, 0);
    ADJLOAD(0, (tc >> 1) + 3, 0); COMPUTE(2, tc + 2);
    WAITX("8"); STAGEH(1, tc + 5); BALLOT(1, (tc >> 1) + 2, 1);
    ADJLOAD(1, (tc >> 1) + 3, 1); COMPUTE(3, tc + 3);
  }
  // ---- tail: t = 60..63 ----
  WAITX("8"); STAGEH(2, 62); BALLOT(0, 31, 0); COMPUTE(0, 60);
  WAITX("4"); STAGEH(3, 63); BALLOT(1, 31, 1); COMPUTE(1, 61);
  WAITX("4"); COMPUTE(2, 62);
  WAITX("0"); COMPUTE(3, 63);

#undef STAGEH
#undef ADJLOAD
#undef BALLOT
#undef COMPUTE
#undef WAITX

  // den: sum across the 4 k-groups
  den0 += __shfl_xor(den0, 16);
  den0 += __shfl_xor(den0, 32);
  den1 += __shfl_xor(den1, 16);
  den1 += __shfl_xor(den1, 32);
  float rdiv0[4], rdiv1[4];
#pragma unroll
  for (int r = 0; r < 4; ++r) {
    rdiv0[r] = 1.0f / __shfl(den0, kg * 4 + r);
    rdiv1[r] = 1.0f / __shfl(den1, kg * 4 + r);
  }

  float* outb = out + ((long)b * NN + (long)it * 32) * ND;
#pragma unroll
  for (int f = 0; f < 4; ++f) {
    int dcol = wid * 64 + f * 16 + lrow;
#pragma unroll
    for (int r = 0; r < 4; ++r) {
      int rr = kg * 4 + r;
      outb[(long)rr * ND + dcol] = acc[0][f][r] * rdiv0[r];
      outb[(long)(16 + rr) * ND + dcol] = acc[1][f][r] * rdiv1[r];
    }
  }
}

// ---------------------------------------------------------------------------
extern "C" void kernel_launch(void* const* d_in, const int* in_sizes, int n_in,
                              void* d_out, int out_size, void* d_ws,
                              size_t ws_size, hipStream_t stream) {
  const float* x = (const float*)d_in[0];
  const int* adj = (const int*)d_in[1];
  const float* W = (const float*)d_in[2];
  const float* a = (const float*)d_in[3];
  float* out = (float*)d_out;

  char* ws = (char*)d_ws;
  const size_t base = 8u * 1024u * 1024u;
  __bf16* hT2 = (__bf16*)ws;                  // 8 MB
  float* elc = (float*)(ws + base);           // 64 KB
  float* erx = (float*)(ws + base + 65536u);  // 64 KB

  k1_h<<<dim3(512), dim3(256), 0, stream>>>(x, W, hT2);
  k2_elr<<<dim3(256), dim3(256), 0, stream>>>(x, W, a, elc, erx);
  k3_main<<<dim3(512), dim3(256), 0, stream>>>(adj, hT2, elc, erx, out);
}

// Round 10
// 113.489 us; speedup vs baseline: 1.1617x; 1.1058x over previous
//
#include <hip/hip_runtime.h>
#include <hip/hip_bf16.h>

typedef __attribute__((ext_vector_type(8))) __bf16 bf16x8;
typedef __attribute__((ext_vector_type(4))) float f32x4;
typedef __attribute__((ext_vector_type(4))) int int4v;

#define NB 8
#define NN 2048
#define ND 256
#define L2E 1.44269504f
#define AS1 __attribute__((address_space(1)))
#define AS3 __attribute__((address_space(3)))

// ---------------------------------------------------------------------------
// K2: per block recompute wl/wr = W^T a halves (L2-hot W), then row dots.
//   elc[bn] = (-0.8*el - 16) * log2e
//   erx[bn] = (er - 16) * log2e        (x02 = 0.2*x16 + 3.2*log2e in k3)
// ---------------------------------------------------------------------------
__global__ __launch_bounds__(256) void k2_elr(
    const float* __restrict__ x, const float* __restrict__ W,
    const float* __restrict__ a, float* __restrict__ elc,
    float* __restrict__ erx) {
  __shared__ float wls[ND], wrs[ND];
  int t = threadIdx.x;
  {
    float swl = 0.f, swr = 0.f;
    for (int o = 0; o < ND; ++o) {
      float wv = W[(long)o * ND + t];
      swl = fmaf(a[o], wv, swl);
      swr = fmaf(a[ND + o], wv, swr);
    }
    wls[t] = swl;
    wrs[t] = swr;
  }
  __syncthreads();
  int r = t >> 2, q = t & 3;
  long row = (long)blockIdx.x * 64 + r;
  const f32x4* xr = (const f32x4*)(x + row * ND);
  float sl = 0.f, sr = 0.f;
#pragma unroll
  for (int ii = 0; ii < 16; ++ii) {
    int idx = q + (ii << 2);
    f32x4 xv = xr[idx];
    f32x4 lv = *(const f32x4*)(wls + idx * 4);
    f32x4 rv = *(const f32x4*)(wrs + idx * 4);
    sl += xv[0] * lv[0] + xv[1] * lv[1] + xv[2] * lv[2] + xv[3] * lv[3];
    sr += xv[0] * rv[0] + xv[1] * rv[1] + xv[2] * rv[2] + xv[3] * rv[3];
  }
  sl += __shfl_xor(sl, 1);
  sl += __shfl_xor(sl, 2);
  sr += __shfl_xor(sr, 1);
  sr += __shfl_xor(sr, 2);
  if (q == 0) {
    elc[row] = (-0.8f * sl - 16.0f) * L2E;
    erx[row] = (sr - 16.0f) * L2E;
  }
}

// ---------------------------------------------------------------------------
// K1: h = x @ W^T via bf16 MFMA; write hT2[b][jc][d][32] bf16 (chunk-
// contiguous: one 32-j chunk x 256 d = 16 KB sequential block).
// ---------------------------------------------------------------------------
__global__ __launch_bounds__(256) void k1_h(
    const float* __restrict__ x, const float* __restrict__ W,
    __bf16* __restrict__ hT2) {
  __shared__ __bf16 hlds[256 * 34];
  int tid = threadIdx.x;
  int wid = tid >> 6, lane = tid & 63;
  int msub = wid & 1, nh = wid >> 1;
  int lrow = lane & 15, kg = lane >> 4;
  int m0 = blockIdx.x * 32;
  int row = m0 + msub * 16 + lrow;

  f32x4 acc[8];
#pragma unroll
  for (int f = 0; f < 8; ++f) acc[f] = (f32x4){0.f, 0.f, 0.f, 0.f};

#pragma unroll
  for (int k0 = 0; k0 < ND; k0 += 32) {
    int kk = k0 + kg * 8;
    const f32x4* xa = (const f32x4*)(x + (long)row * ND + kk);
    f32x4 a0 = xa[0], a1 = xa[1];
    bf16x8 afrag;
    afrag[0] = (__bf16)a0[0]; afrag[1] = (__bf16)a0[1];
    afrag[2] = (__bf16)a0[2]; afrag[3] = (__bf16)a0[3];
    afrag[4] = (__bf16)a1[0]; afrag[5] = (__bf16)a1[1];
    afrag[6] = (__bf16)a1[2]; afrag[7] = (__bf16)a1[3];
#pragma unroll
    for (int f = 0; f < 8; ++f) {
      int o = nh * 128 + f * 16 + lrow;
      const f32x4* wb = (const f32x4*)(W + (long)o * ND + kk);
      f32x4 b0 = wb[0], b1 = wb[1];
      bf16x8 bfrag;
      bfrag[0] = (__bf16)b0[0]; bfrag[1] = (__bf16)b0[1];
      bfrag[2] = (__bf16)b0[2]; bfrag[3] = (__bf16)b0[3];
      bfrag[4] = (__bf16)b1[0]; bfrag[5] = (__bf16)b1[1];
      bfrag[6] = (__bf16)b1[2]; bfrag[7] = (__bf16)b1[3];
      acc[f] = __builtin_amdgcn_mfma_f32_16x16x32_bf16(afrag, bfrag, acc[f], 0, 0, 0);
    }
  }

#pragma unroll
  for (int f = 0; f < 8; ++f) {
    int d = nh * 128 + f * 16 + lrow;
#pragma unroll
    for (int r = 0; r < 4; ++r) {
      int nloc = msub * 16 + kg * 4 + r;
      hlds[d * 34 + nloc] = (__bf16)acc[f][r];
    }
  }
  __syncthreads();
  {
    int b = m0 >> 11;
    int jc = (m0 & (NN - 1)) >> 5;
    const int* src = (const int*)(hlds + tid * 34);
    int tmp[16];
#pragma unroll
    for (int j = 0; j < 16; ++j) tmp[j] = src[j];
    __bf16* dst = hT2 + (((long)b * 64 + jc) * 256 + tid) * 32;
#pragma unroll
    for (int j = 0; j < 4; ++j)
      *(int4v*)(dst + j * 8) = *(int4v*)(tmp + j * 4);
  }
}

// ---------------------------------------------------------------------------
// K3: fused mask + softmax + PV with j-chunk wave split (no exp 4x-dup, no
// ballot). 256 thr = 4 waves: wave (jw=w>>1, dw=w&1) computes chunks of
// parity jw on d-half dw. Superphase = 2 chunks; LDS ring = 2 superphases x
// 4 slices x 8 KB. Per body: drain vmcnt(0)+barrier, adj prefetch (4 int4,
// next superphase), stage next superphase (8 gload_lds, r6 swizzle pair),
// compute own chunk-half (16 exp2 + 16 MFMA + 10 ds_read).
// Epilogue: jw-pair acc reduction via retired hbuf + den LDS.
// ---------------------------------------------------------------------------
__global__ __launch_bounds__(256, 2) void k3_main(
    const int* __restrict__ adj, const __bf16* __restrict__ hT2,
    const float* __restrict__ elc, const float* __restrict__ erx,
    float* __restrict__ out) {
  __shared__ __bf16 hbuf[2][4][4096];  // 64 KB: [phase][slice=jw*2+dw][8 KB]
  __shared__ float er_lds[NN];         // 8 KB
  __shared__ float denb[4][32];        // 0.5 KB

  int blk = blockIdx.x;
  int b = blk & 7;    // batch -> XCD pin
  int it = blk >> 3;  // i-tile 0..63
  int tid = threadIdx.x;
  int wid = tid >> 6, lane = tid & 63;
  int jw = wid >> 1, dw = wid & 1;
  int lrow = lane & 15, kg = lane >> 4, kg8 = kg * 8;

  const __bf16* hT2b = hT2 + (long)b * 64 * 8192;
  const int* adjr0 = adj + ((long)b * NN + it * 32 + lrow) * NN;
  const int* adjr1 = adjr0 + 16 * NN;
  const float* erxb = erx + (long)b * NN;
  float c1s0 = elc[b * NN + it * 32 + lrow];
  float c1s1 = elc[b * NN + it * 32 + 16 + lrow];

  // er -> LDS (2 gload_lds; drained by body0's vmcnt(0))
  __builtin_amdgcn_global_load_lds((const AS1 void*)(erxb + tid * 4),
                                   (AS3 void*)(er_lds + tid * 4), 16, 0, 0);
  __builtin_amdgcn_global_load_lds((const AS1 void*)(erxb + 1024 + tid * 4),
                                   (AS3 void*)(er_lds + 1024 + tid * 4), 16, 0, 0);

  // stage addressing (r6-proven pair): per inst s: slice = s>>1 holds chunk
  // 2*SP + (s>>2), d-half (s>>1)&1; src elem = (s&1)*2048 + (tid>>2)*32 + jlog*8
  int jlog = (tid & 3) ^ ((tid >> 3) & 3);
  int stoff = (tid >> 2) * 32 + jlog * 8;
  // ds_read: byte = (f*16+lrow)*64 + (kg^((lrow>>1)&3))*16
  int hoff = lrow * 64 + (kg ^ ((lrow >> 1) & 3)) * 16;

  f32x4 acc0[8], acc1[8];
#pragma unroll
  for (int f = 0; f < 8; ++f) {
    acc0[f] = (f32x4){0.f, 0.f, 0.f, 0.f};
    acc1[f] = (f32x4){0.f, 0.f, 0.f, 0.f};
  }
  float den0 = 0.f, den1 = 0.f;
  int4v av0_0, av0_1, av0_2, av0_3, av1_0, av1_1, av1_2, av1_3;

#define STAGE(PH, SP)                                                         \
  {                                                                           \
    long cb_ = (long)(2 * (SP)) * 8192;                                       \
    _Pragma("unroll") for (int s = 0; s < 8; ++s) {                           \
      const __bf16* src_ = hT2b + cb_ + (s >> 2) * 8192 + ((s >> 1) & 1) * 4096 \
                           + (s & 1) * 2048 + stoff;                          \
      __builtin_amdgcn_global_load_lds(                                       \
          (const AS1 void*)src_,                                              \
          (AS3 void*)(&hbuf[PH][s >> 1][(s & 1) * 2048 + tid * 8]), 16, 0, 0); \
    }                                                                         \
  }

#define ADJL(SET, SP)                                                         \
  {                                                                           \
    const int* a0_ = adjr0 + (long)(2 * (SP) + jw) * 32 + kg8;                \
    const int* a1_ = adjr1 + (long)(2 * (SP) + jw) * 32 + kg8;                \
    av##SET##_0 = *(const int4v*)a0_;                                         \
    av##SET##_1 = *(const int4v*)(a0_ + 4);                                   \
    av##SET##_2 = *(const int4v*)a1_;                                         \
    av##SET##_3 = *(const int4v*)(a1_ + 4);                                   \
  }

#define COMP(PH, SET, SP)                                                     \
  {                                                                           \
    const float* ep_ = er_lds + (2 * (SP) + jw) * 32 + kg8;                   \
    f32x4 xa_ = *(const f32x4*)ep_;                                           \
    f32x4 xb_ = *(const f32x4*)(ep_ + 4);                                     \
    bf16x8 pf0, pf1;                                                          \
    float ps0 = 0.f, ps1 = 0.f;                                               \
    _Pragma("unroll") for (int e = 0; e < 8; ++e) {                           \
      float x16 = (e < 4) ? xa_[e] : xb_[e - 4];                              \
      float x02 = fmaf(0.2f, x16, 4.61662413f);                               \
      int a0v = (e < 4) ? av##SET##_0[e] : av##SET##_1[e - 4];                \
      int a1v = (e < 4) ? av##SET##_2[e] : av##SET##_3[e - 4];                \
      float m0_ = fmaxf(x16, x02 + c1s0);                                     \
      float m1_ = fmaxf(x16, x02 + c1s1);                                     \
      float p0 = __builtin_amdgcn_exp2f(m0_);                                 \
      float p1 = __builtin_amdgcn_exp2f(m1_);                                 \
      p0 = a0v ? p0 : 0.0f;                                                   \
      p1 = a1v ? p1 : 0.0f;                                                   \
      ps0 += p0; ps1 += p1;                                                   \
      pf0[e] = (__bf16)p0; pf1[e] = (__bf16)p1;                               \
    }                                                                         \
    den0 += ps0; den1 += ps1;                                                 \
    const char* hb_ = (const char*)&hbuf[PH][wid][0];                         \
    __builtin_amdgcn_s_setprio(1);                                            \
    _Pragma("unroll") for (int f = 0; f < 8; ++f) {                           \
      bf16x8 bfr = *(const bf16x8*)(hb_ + hoff + f * 1024);                   \
      acc0[f] = __builtin_amdgcn_mfma_f32_16x16x32_bf16(pf0, bfr, acc0[f], 0, 0, 0); \
      acc1[f] = __builtin_amdgcn_mfma_f32_16x16x32_bf16(pf1, bfr, acc1[f], 0, 0, 0); \
    }                                                                         \
    __builtin_amdgcn_s_setprio(0);                                            \
  }

#define WAIT0                                         \
  asm volatile("s_waitcnt vmcnt(0)" ::: "memory");    \
  __builtin_amdgcn_s_barrier();

  // prologue: adj sp0 -> set0, stage sp0 -> phase0
  ADJL(0, 0);
  STAGE(0, 0);

  for (int T = 0; T < 15; ++T) {
    int ke = 2 * T;  // even body
    WAIT0; ADJL(1, ke + 1); STAGE(1, ke + 1); COMP(0, 0, ke);
    WAIT0; ADJL(0, ke + 2); STAGE(0, ke + 2); COMP(1, 1, ke + 1);
  }
  // tail: bodies 30, 31
  WAIT0; ADJL(1, 31); STAGE(1, 31); COMP(0, 0, 30);
  WAIT0; COMP(1, 1, 31);

#undef STAGE
#undef ADJL
#undef COMP
#undef WAIT0

  // ---- epilogue: den + jw-pair acc reduction ----
  den0 += __shfl_xor(den0, 16);
  den0 += __shfl_xor(den0, 32);
  den1 += __shfl_xor(den1, 16);
  den1 += __shfl_xor(den1, 32);
  if (lane < 16) {
    denb[wid][lane] = den0;
    denb[wid][16 + lane] = den1;
  }
  // jw=0 waves park their acc in retired phase-0 LDS (32 KB region)
  float* accbuf = (float*)&hbuf[0][0][0];
  if (jw == 0) {
#pragma unroll
    for (int f = 0; f < 8; ++f)
#pragma unroll
      for (int r = 0; r < 4; ++r) {
        accbuf[dw * 4096 + (kg * 4 + r) * 128 + f * 16 + lrow] = acc0[f][r];
        accbuf[dw * 4096 + (16 + kg * 4 + r) * 128 + f * 16 + lrow] = acc1[f][r];
      }
  }
  __syncthreads();
  if (jw == 1) {
    float rd0[4], rd1[4];
#pragma unroll
    for (int r = 0; r < 4; ++r) {
      int r0 = kg * 4 + r;
      rd0[r] = 1.0f / (denb[dw][r0] + denb[2 + dw][r0]);
      rd1[r] = 1.0f / (denb[dw][16 + r0] + denb[2 + dw][16 + r0]);
    }
    float* ob = out + ((long)b * NN + it * 32) * ND + dw * 128;
#pragma unroll
    for (int f = 0; f < 8; ++f)
#pragma unroll
      for (int r = 0; r < 4; ++r) {
        int r0 = kg * 4 + r;
        int dcol = f * 16 + lrow;
        float v0 = acc0[f][r] + accbuf[dw * 4096 + r0 * 128 + dcol];
        float v1 = acc1[f][r] + accbuf[dw * 4096 + (16 + r0) * 128 + dcol];
        ob[(long)r0 * ND + dcol] = v0 * rd0[r];
        ob[(long)(16 + r0) * ND + dcol] = v1 * rd1[r];
      }
  }
}

// ---------------------------------------------------------------------------
extern "C" void kernel_launch(void* const* d_in, const int* in_sizes, int n_in,
                              void* d_out, int out_size, void* d_ws,
                              size_t ws_size, hipStream_t stream) {
  const float* x = (const float*)d_in[0];
  const int* adj = (const int*)d_in[1];
  const float* W = (const float*)d_in[2];
  const float* a = (const float*)d_in[3];
  float* out = (float*)d_out;

  char* ws = (char*)d_ws;
  const size_t base = 8u * 1024u * 1024u;
  __bf16* hT2 = (__bf16*)ws;                  // 8 MB
  float* elc = (float*)(ws + base);           // 64 KB
  float* erx = (float*)(ws + base + 65536u);  // 64 KB

  k1_h<<<dim3(512), dim3(256), 0, stream>>>(x, W, hT2);
  k2_elr<<<dim3(256), dim3(256), 0, stream>>>(x, W, a, elc, erx);
  k3_main<<<dim3(512), dim3(256), 0, stream>>>(adj, hT2, elc, erx, out);
}